// Round 8
// baseline (750.734 us; speedup 1.0000x reference)
//
#include <hip/hip_runtime.h>
#include <hip/hip_bf16.h>
#include <cstdint>
#include <cstddef>

#define ALPHA 0.2f
#define MLP_SLOPE 0.01f

typedef short bf16x8 __attribute__((ext_vector_type(8)));
typedef float f32x4 __attribute__((ext_vector_type(4)));
typedef unsigned short ushort_t;

// raw barrier: syncs LDS exchange WITHOUT draining vmcnt (global prefetches
// stay in flight across it).
#define ASM_BARRIER() __asm__ __volatile__("s_waitcnt lgkmcnt(0)\n\ts_barrier" ::: "memory")

__device__ __forceinline__ float lrelu(float x, float s) { return x > 0.f ? x : x * s; }
__device__ __forceinline__ ushort_t f2bf(float x) {
  __hip_bfloat16 h = __float2bfloat16(x);
  return *reinterpret_cast<ushort_t*>(&h);
}
__device__ __forceinline__ float bf2f(ushort_t u) {
  union { unsigned int i; float f; } v; v.i = ((unsigned int)u) << 16; return v.f;
}

// ---------------------------------------------------------------------------
// split fp32 -> (hi, lo) bf16, elementwise (4 elems/thread)
// ---------------------------------------------------------------------------
__global__ __launch_bounds__(256) void split_f(
    const float* __restrict__ in, ushort_t* __restrict__ hi,
    ushort_t* __restrict__ lo)
{
  int idx = blockIdx.x * 256 + threadIdx.x;
  float4 v = ((const float4*)in)[idx];
  ushort4 h, l;
  h.x = f2bf(v.x); l.x = f2bf(v.x - bf2f(h.x));
  h.y = f2bf(v.y); l.y = f2bf(v.y - bf2f(h.y));
  h.z = f2bf(v.z); l.z = f2bf(v.z - bf2f(h.z));
  h.w = f2bf(v.w); l.w = f2bf(v.w - bf2f(h.w));
  ((ushort4*)hi)[idx] = h;
  ((ushort4*)lo)[idx] = l;
}

// ---------------------------------------------------------------------------
// Pack weights W[K,N] (batch via blockIdx.y) into MFMA B-fragment order
// ---------------------------------------------------------------------------
__global__ __launch_bounds__(256) void pack_wt(
    const float* __restrict__ W, ushort_t* __restrict__ hi,
    ushort_t* __restrict__ lo, int K, int N)
{
  int gid = blockIdx.x * 256 + threadIdx.x;   // [0, N*K/8)
  int lane = gid & 63;
  int kbc = K >> 5;
  int kblk = (gid >> 6) % kbc;
  int nblk = (gid >> 6) / kbc;
  size_t b = (size_t)blockIdx.y * K * N;
  int col = nblk * 16 + (lane & 15);
  int krow = kblk * 32 + (lane >> 4) * 8;
  ushort_t h[8] __attribute__((aligned(16)));
  ushort_t l[8] __attribute__((aligned(16)));
#pragma unroll
  for (int e = 0; e < 8; ++e) {
    float v = W[b + (size_t)(krow + e) * N + col];
    h[e] = f2bf(v);
    l[e] = f2bf(v - bf2f(h[e]));
  }
  *(uint4*)&hi[b + (size_t)gid * 8] = *(uint4*)h;
  *(uint4*)&lo[b + (size_t)gid * 8] = *(uint4*)l;
}

// ---------------------------------------------------------------------------
// LDS-free split-bf16 MFMA GEMM: C = act(A[M,K] @ W + bias).  (unchanged R5)
// ---------------------------------------------------------------------------
__global__ __launch_bounds__(256) void gemm_nolds(
    const ushort_t* __restrict__ Ahi, const ushort_t* __restrict__ Alo,
    const ushort_t* __restrict__ Bph, const ushort_t* __restrict__ Bpl,
    const float* __restrict__ bias, float* __restrict__ Cf,
    ushort_t* __restrict__ Chi, ushort_t* __restrict__ Clo,
    int M, int N, int K, float slope, int act)
{
  const size_t boff = (size_t)blockIdx.z * N * K;
  const size_t coff = (size_t)blockIdx.z * M * N;
  const int t = threadIdx.x;
  const int wave = t >> 6, l63 = t & 63;
  const int l16 = t & 15, oct = (t >> 4) & 3, quad = oct;
  const int wm = (wave & 1) * 64, wn = (wave >> 1) * 32;
  const int m0 = blockIdx.y * 128 + wm;
  const int nb = blockIdx.x * 4 + (wave >> 1) * 2;
  const int nbase = blockIdx.x * 64 + wn;
  const int ksteps = K >> 5;

  const ushort_t* aph[4];
  const ushort_t* apl[4];
#pragma unroll
  for (int mt = 0; mt < 4; ++mt) {
    size_t o = (size_t)(m0 + mt * 16 + l16) * K + oct * 8;
    aph[mt] = Ahi + o;
    apl[mt] = Alo + o;
  }
  const ushort_t* bph[2];
  const ushort_t* bpl[2];
#pragma unroll
  for (int nt = 0; nt < 2; ++nt) {
    size_t o = boff + ((size_t)(nb + nt) * ksteps * 64 + l63) * 8;
    bph[nt] = Bph + o;
    bpl[nt] = Bpl + o;
  }

  f32x4 acc[4][2];
#pragma unroll
  for (int i = 0; i < 4; ++i)
#pragma unroll
    for (int j = 0; j < 2; ++j) acc[i][j] = (f32x4){0.f, 0.f, 0.f, 0.f};

#define LOADF(AH, AL, BH, BL, KB)                                         \
  {                                                                       \
    _Pragma("unroll") for (int mt = 0; mt < 4; ++mt) {                    \
      AH[mt] = *(const bf16x8*)(aph[mt] + (size_t)(KB) * 32);             \
      AL[mt] = *(const bf16x8*)(apl[mt] + (size_t)(KB) * 32);             \
    }                                                                     \
    _Pragma("unroll") for (int nt = 0; nt < 2; ++nt) {                    \
      BH[nt] = *(const bf16x8*)(bph[nt] + (size_t)(KB) * 512);            \
      BL[nt] = *(const bf16x8*)(bpl[nt] + (size_t)(KB) * 512);            \
    }                                                                     \
  }
#define MF(AH, AL, BH, BL)                                                \
  {                                                                       \
    _Pragma("unroll") for (int mt = 0; mt < 4; ++mt)                      \
    _Pragma("unroll") for (int nt = 0; nt < 2; ++nt) {                    \
      acc[mt][nt] = __builtin_amdgcn_mfma_f32_16x16x32_bf16(AH[mt], BH[nt], acc[mt][nt], 0, 0, 0); \
      acc[mt][nt] = __builtin_amdgcn_mfma_f32_16x16x32_bf16(AH[mt], BL[nt], acc[mt][nt], 0, 0, 0); \
      acc[mt][nt] = __builtin_amdgcn_mfma_f32_16x16x32_bf16(AL[mt], BH[nt], acc[mt][nt], 0, 0, 0); \
    }                                                                     \
  }

  bf16x8 ah0[4], al0[4], bh0[2], bl0[2];
  bf16x8 ah1[4], al1[4], bh1[2], bl1[2];
  LOADF(ah0, al0, bh0, bl0, 0)
  for (int kb = 0; kb < ksteps; kb += 2) {
    LOADF(ah1, al1, bh1, bl1, kb + 1)
    MF(ah0, al0, bh0, bl0)
    if (kb + 2 < ksteps) LOADF(ah0, al0, bh0, bl0, kb + 2)
    MF(ah1, al1, bh1, bl1)
  }
#undef LOADF
#undef MF

#pragma unroll
  for (int mt = 0; mt < 4; ++mt)
#pragma unroll
    for (int nt = 0; nt < 2; ++nt)
#pragma unroll
      for (int rg = 0; rg < 4; ++rg) {
        int m = m0 + mt * 16 + quad * 4 + rg;
        int n = nbase + nt * 16 + l16;
        float v = acc[mt][nt][rg];
        if (bias) v += bias[n];
        if (act) v = lrelu(v, slope);
        size_t o = coff + (size_t)m * N + n;
        if (Cf) Cf[o] = v;
        if (Chi) {
          ushort_t h = f2bf(v);
          Chi[o] = h; Clo[o] = f2bf(v - bf2f(h));
        }
      }
}

// ---------------------------------------------------------------------------
// s1/s2: per-row dots of h with a1/a2 (one wave per row, both heads)
// ---------------------------------------------------------------------------
__global__ __launch_bounds__(256) void s_kernel(
    const float* __restrict__ hbuf, const float* __restrict__ a1,
    const float* __restrict__ a2, float* __restrict__ s1, float* __restrict__ s2)
{
  const int gw = (blockIdx.x * 256 + threadIdx.x) >> 6;
  const int lane = threadIdx.x & 63;
#pragma unroll
  for (int hh = 0; hh < 2; ++hh) {
    float4 hv = ((const float4*)(hbuf + ((size_t)hh * 8192 + gw) * 256))[lane];
    float4 a1v = ((const float4*)(a1 + hh * 256))[lane];
    float4 a2v = ((const float4*)(a2 + hh * 256))[lane];
    float p1 = hv.x * a1v.x + hv.y * a1v.y + hv.z * a1v.z + hv.w * a1v.w;
    float p2 = hv.x * a2v.x + hv.y * a2v.y + hv.z * a2v.z + hv.w * a2v.w;
    for (int off = 32; off > 0; off >>= 1) {
      p1 += __shfl_xor(p1, off);
      p2 += __shfl_xor(p2, off);
    }
    if (lane == 0) {
      s1[hh * 8192 + gw] = p1;
      s2[hh * 8192 + gw] = p2;
    }
  }
}

// ---------------------------------------------------------------------------
// Pack h (fp32 [head][j][c]) into MFMA B-fragment order (bf16)
// ---------------------------------------------------------------------------
__global__ __launch_bounds__(256) void h_pack(
    const float* __restrict__ hbuf, ushort_t* __restrict__ Bpack)
{
  int gid = blockIdx.x * 256 + threadIdx.x;   // 0 .. 524287
  int lane = gid & 63;
  int ntile = (gid >> 6) & 15;
  int kblk = (gid >> 10) & 255;
  int head = gid >> 18;
  int c = ntile * 16 + (lane & 15);
  int jb = kblk * 32 + (lane >> 4) * 8;
  ushort_t o[8] __attribute__((aligned(16)));
#pragma unroll
  for (int e = 0; e < 8; ++e)
    o[e] = f2bf(hbuf[((size_t)head * 8192 + jb + e) * 256 + c]);
  *(uint4*)&Bpack[(size_t)gid * 8] = *(uint4*)o;
}

// ---------------------------------------------------------------------------
// MFMA attention v7: 32-ROW BLOCKS for occupancy. Block = 32 rows x 256 cols
// x 2 heads, 4 waves = (head, 128-col half), acc 64 AGPR/wave; with
// __launch_bounds__(256,3) -> 3 blocks/CU (12 waves) whose phases interleave
// (blocks are not barrier-coupled), unlike R5-R7's 2 lockstepped blocks.
// Generator thread handles ONE head (8 exps). adj read once per block
// (head-duplicate lanes hit the same cacheline -> merged by TA).
// Double-buffered LDS W, lgkm-only barrier, B-frags from L2-resident Bpack.
// Grid (256 rowblocks, 4 k-slices of 2048).
// ---------------------------------------------------------------------------
__global__ __launch_bounds__(256, 3) void attn_mfma7(
    const ushort_t* __restrict__ Bpack, const float* __restrict__ s1g,
    const float* __restrict__ s2g, const int* __restrict__ adj,
    ushort_t* __restrict__ pacc, float* __restrict__ pl)
{
  __shared__ ushort_t Wlds[2][2][2][64][8];   // [buf][head][mt][lane][8]
  const int t = threadIdx.x;
  const int i0 = blockIdx.x * 32;
  const int js = blockIdx.y;
  const int kbase = js * 2048;
  // generator mapping: row wr (0..31), head ghead, k-octet kq (0..3)
  const int wr = t >> 3;
  const int ghead = (t >> 2) & 1;
  const int kq = t & 3;
  const int glane = kq * 16 + (wr & 15);
  const int gmt = wr >> 4;
  const float s1v = s1g[(size_t)ghead * 8192 + i0 + wr];
  const float* s2h = s2g + (size_t)ghead * 8192;
  const int* arow = adj + (size_t)(i0 + wr) * 8192;
  // consumer mapping
  const int wave = t >> 6, head = wave >> 1, nh = wave & 1;
  const int l16 = t & 15, quad = (t >> 4) & 3;
  const int l63 = t & 63;
  f32x4 acc[2][8];
#pragma unroll
  for (int m = 0; m < 2; ++m)
#pragma unroll
    for (int n = 0; n < 8; ++n) acc[m][n] = (f32x4){0.f, 0.f, 0.f, 0.f};
  float rs = 0.f;

  int4 pa0, pa1;
  float4 ps2a, ps2b;
  auto fetch = [&](int kk) {
    pa0 = *(const int4*)&arow[kk];
    pa1 = *(const int4*)&arow[kk + 4];
    ps2a = *(const float4*)&s2h[kk];
    ps2b = *(const float4*)&s2h[kk + 4];
  };
  auto gen = [&](int buf) {
    int am[8] = {pa0.x, pa0.y, pa0.z, pa0.w, pa1.x, pa1.y, pa1.z, pa1.w};
    float s2v[8] = {ps2a.x, ps2a.y, ps2a.z, ps2a.w,
                    ps2b.x, ps2b.y, ps2b.z, ps2b.w};
    ushort_t w[8] __attribute__((aligned(16)));
#pragma unroll
    for (int e = 0; e < 8; ++e) {
      float ev = s1v + s2v[e];
      ev = fmaxf(ev, 0.f) + ALPHA * fminf(ev, 0.f);
      float wv = am[e] > 0 ? __expf(ev) : 0.f;
      rs += wv;
      w[e] = f2bf(wv);
    }
    *(uint4*)&Wlds[buf][ghead][gmt][glane][0] = *(uint4*)w;
  };

  // prologue
  fetch(kbase + kq * 8);
  gen(0);
  fetch(kbase + 32 + kq * 8);
  ASM_BARRIER();

  for (int kt = 0; kt < 64; ++kt) {
    const int cur = kt & 1, nxt = cur ^ 1;
    // B-fragment loads for this step (L2-resident Bpack)
    const int kblk = js * 64 + kt;
    const ushort_t* bb =
        Bpack + ((((size_t)head * 256 + kblk) * 16 + nh * 8) * 64 + l63) * 8;
    bf16x8 Bf[8];
#pragma unroll
    for (int nt = 0; nt < 8; ++nt)
      Bf[nt] = *(const bf16x8*)&bb[nt * 512];
    // A-fragments from LDS
    bf16x8 Af[2];
#pragma unroll
    for (int mt = 0; mt < 2; ++mt)
      Af[mt] = *(const bf16x8*)&Wlds[cur][head][mt][l63][0];
    // MFMA burst (16)
#pragma unroll
    for (int mt = 0; mt < 2; ++mt)
#pragma unroll
      for (int nt = 0; nt < 8; ++nt)
        acc[mt][nt] = __builtin_amdgcn_mfma_f32_16x16x32_bf16(
            Af[mt], Bf[nt], acc[mt][nt], 0, 0, 0);
    // generate next step's W; prefetch step kt+2
    if (kt < 63) {
      gen(nxt);
      if (kt < 62) fetch(kbase + (kt + 2) * 32 + kq * 8);
    }
    ASM_BARRIER();
  }

  // denominators: reduce across the 4 kq lanes of each (row, head)
  rs += __shfl_xor(rs, 1); rs += __shfl_xor(rs, 2);
  if (kq == 0)
    pl[((size_t)js * 2 + ghead) * 8192 + i0 + wr] = rs;

  // store bf16 partial numerators
  const int n0 = nh * 128;
#pragma unroll
  for (int mt = 0; mt < 2; ++mt)
#pragma unroll
    for (int nt = 0; nt < 8; ++nt)
#pragma unroll
      for (int rg = 0; rg < 4; ++rg) {
        int row = i0 + mt * 16 + quad * 4 + rg;
        int col = n0 + nt * 16 + l16;
        pacc[(((size_t)js * 2 + head) * 8192 + row) * 256 + col] =
            f2bf(acc[mt][nt][rg]);
      }
}

// ---------------------------------------------------------------------------
// Finalize (+ fused llm copy): shuffle-based reduction, single barrier.
// ---------------------------------------------------------------------------
__global__ __launch_bounds__(256) void attn_finalize(
    const ushort_t* __restrict__ pacc, const float* __restrict__ pl,
    const float* __restrict__ bg, const float* __restrict__ llm,
    float* __restrict__ embed)
{
  __shared__ float red[8];
  const int r = blockIdx.x;
  const int t = threadIdx.x;
  const int wv = t >> 6, lane = t & 63;
  if (t < 128)
    *(float4*)&embed[(size_t)r * 768 + t * 4] =
        *(const float4*)&llm[(size_t)r * 512 + t * 4];
  float o[2];
#pragma unroll
  for (int hh = 0; hh < 2; ++hh) {
    float num = 0.f, l = 0.f;
#pragma unroll
    for (int js = 0; js < 4; ++js) {
      num += bf2f(pacc[(((size_t)js * 2 + hh) * 8192 + r) * 256 + t]);
      l += pl[((size_t)js * 2 + hh) * 8192 + r];
    }
    o[hh] = lrelu(num / l, ALPHA);
  }
  float v0 = o[0] * o[0], v1 = o[1] * o[1];
  for (int off = 32; off > 0; off >>= 1) {
    v0 += __shfl_xor(v0, off);
    v1 += __shfl_xor(v1, off);
  }
  if (lane == 0) { red[wv] = v0; red[4 + wv] = v1; }
  __syncthreads();
  float n0 = fmaxf(sqrtf(red[0] + red[1] + red[2] + red[3]), 1e-12f);
  float n1 = fmaxf(sqrtf(red[4] + red[5] + red[6] + red[7]), 1e-12f);
  embed[(size_t)r * 768 + 512 + t] =
      0.5f * (o[0] / n0 + bg[t] + o[1] / n1 + bg[256 + t]);
}

// ---------------------------------------------------------------------------
__global__ __launch_bounds__(256) void pred_kernel(
    const float* __restrict__ z2, const int* __restrict__ ts,
    float* __restrict__ out, int E)
{
  const int gw = (blockIdx.x * 256 + threadIdx.x) >> 6;
  const int lane = threadIdx.x & 63;
  if (gw >= E) return;
  const int a = ts[gw * 2], b = ts[gw * 2 + 1];
  float4 va = ((const float4*)(z2 + (size_t)a * 256))[lane];
  float4 vb = ((const float4*)(z2 + (size_t)b * 256))[lane];
  float p = va.x * vb.x + va.y * vb.y + va.z * vb.z + va.w * vb.w;
  for (int off = 32; off > 0; off >>= 1) p += __shfl_xor(p, off);
  if (lane == 0) out[gw] = p;
}

// ---------------------------------------------------------------------------
extern "C" void kernel_launch(void* const* d_in, const int* in_sizes, int n_in,
                              void* d_out, int out_size, void* d_ws, size_t ws_size,
                              hipStream_t stream) {
  const float* x   = (const float*)d_in[0];
  const int*   adj = (const int*)d_in[1];
  const int*   ts  = (const int*)d_in[2];
  const float* llm = (const float*)d_in[3];
  const float* Wg  = (const float*)d_in[4];
  const float* a1  = (const float*)d_in[5];
  const float* a2  = (const float*)d_in[6];
  const float* bg  = (const float*)d_in[7];
  const float* W1  = (const float*)d_in[8];
  const float* b1  = (const float*)d_in[9];
  const float* W2  = (const float*)d_in[10];
  const float* b2  = (const float*)d_in[11];
  float* out = (float*)d_out;
  float* ws  = (float*)d_ws;
  const int E = in_sizes[2] / 2;

  // ---- workspace layout (float words), with lifetime overlays ----
  float*    hbuf  = ws;                             // [0, 4194304)
  ushort_t* Bpack = (ushort_t*)(ws + 4194304);      // [4194304, 6291456)
  float*    embed = ws;                             // overlay hbuf+Bpack
  ushort_t* xhi   = (ushort_t*)(ws + 6291456);
  ushort_t* xlo   = (ushort_t*)(ws + 8388608);
  ushort_t* z1hi  = xhi;                            // overlay (x dead)
  ushort_t* z1lo  = xlo;
  float*    s1    = ws + 10485760;
  float*    s2    = ws + 10502144;
  float*    pl    = ws + 10518528;
  ushort_t* pacc  = (ushort_t*)(ws + 10584064);
  ushort_t* ehi   = (ushort_t*)(ws + 10584064);     // overlay pacc (dead)
  ushort_t* elo   = (ushort_t*)(ws + 13729792);
  float*    z2    = ws + 16875520;
  ushort_t* wgphi = (ushort_t*)(ws + 18972672);     // 2*256*512
  ushort_t* wgplo = (ushort_t*)(ws + 19103744);
  ushort_t* w1phi = (ushort_t*)(ws + 19234816);     // 512*768
  ushort_t* w1plo = (ushort_t*)(ws + 19431424);
  ushort_t* w2phi = (ushort_t*)(ws + 19628032);     // 256*512
  ushort_t* w2plo = (ushort_t*)(ws + 19693568);

  // 1. splits / weight packing
  split_f<<<4096, 256, 0, stream>>>(x, xhi, xlo);
  pack_wt<<<dim3(64, 2), 256, 0, stream>>>(Wg, wgphi, wgplo, 512, 256);
  pack_wt<<<dim3(192, 1), 256, 0, stream>>>(W1, w1phi, w1plo, 768, 512);
  pack_wt<<<dim3(64, 1), 256, 0, stream>>>(W2, w2phi, w2plo, 512, 256);
  // 2. h[head] = x @ Wg[head]  (LDS-free split GEMM, fp32 out)
  gemm_nolds<<<dim3(4, 64, 2), 256, 0, stream>>>(
      xhi, xlo, wgphi, wgplo, nullptr, hbuf, nullptr, nullptr,
      8192, 256, 512, 0.f, 0);
  // 3. s1/s2 row dots
  s_kernel<<<2048, 256, 0, stream>>>(hbuf, a1, a2, s1, s2);
  // 4. pack h into B-fragment order
  h_pack<<<2048, 256, 0, stream>>>(hbuf, Bpack);
  // 5. MFMA attention partials (32-row blocks, 3 blocks/CU)
  attn_mfma7<<<dim3(256, 4), 256, 0, stream>>>(Bpack, s1, s2, adj, pacc, pl);
  // 6. embed = [llm | attn epilogue]
  attn_finalize<<<8192, 256, 0, stream>>>(pacc, pl, bg, llm, embed);
  // 7. split embed (pacc dead now)
  split_f<<<6144, 256, 0, stream>>>(embed, ehi, elo);
  // 8. z1 = LR(embed @ W1 + b1) -> hi/lo bf16 directly
  gemm_nolds<<<dim3(8, 64, 1), 256, 0, stream>>>(
      ehi, elo, w1phi, w1plo, b1, nullptr, z1hi, z1lo,
      8192, 512, 768, MLP_SLOPE, 1);
  // 9. z2 = LR(z1 @ W2 + b2) fp32
  gemm_nolds<<<dim3(4, 64, 1), 256, 0, stream>>>(
      z1hi, z1lo, w2phi, w2plo, b2, z2, nullptr, nullptr,
      8192, 256, 512, MLP_SLOPE, 1);
  // 10. edge dots
  pred_kernel<<<(E * 64 + 255) / 256, 256, 0, stream>>>(z2, ts, out, E);
}

// Round 9
// 594.484 us; speedup vs baseline: 1.2628x; 1.2628x over previous
//
#include <hip/hip_runtime.h>
#include <hip/hip_bf16.h>
#include <cstdint>
#include <cstddef>

#define ALPHA 0.2f
#define MLP_SLOPE 0.01f

typedef short bf16x8 __attribute__((ext_vector_type(8)));
typedef float f32x4 __attribute__((ext_vector_type(4)));
typedef unsigned short ushort_t;

// raw barrier: syncs LDS exchange WITHOUT draining vmcnt (global prefetches
// stay in flight across it). Used only by attn_mfma6 (R7-best, kept frozen).
#define ASM_BARRIER() __asm__ __volatile__("s_waitcnt lgkmcnt(0)\n\ts_barrier" ::: "memory")

__device__ __forceinline__ float lrelu(float x, float s) { return x > 0.f ? x : x * s; }
__device__ __forceinline__ ushort_t f2bf(float x) {
  __hip_bfloat16 h = __float2bfloat16(x);
  return *reinterpret_cast<ushort_t*>(&h);
}
__device__ __forceinline__ float bf2f(ushort_t u) {
  union { unsigned int i; float f; } v; v.i = ((unsigned int)u) << 16; return v.f;
}

// ---------------------------------------------------------------------------
// cast fp32 -> bf16, 4 elems/thread
// ---------------------------------------------------------------------------
__global__ __launch_bounds__(256) void tobf(
    const float* __restrict__ in, ushort_t* __restrict__ outp)
{
  int idx = blockIdx.x * 256 + threadIdx.x;
  float4 v = ((const float4*)in)[idx];
  ushort4 h;
  h.x = f2bf(v.x); h.y = f2bf(v.y); h.z = f2bf(v.z); h.w = f2bf(v.w);
  ((ushort4*)outp)[idx] = h;
}

// ---------------------------------------------------------------------------
// zero a float buffer (s1/s2 init for atomics)
// ---------------------------------------------------------------------------
__global__ __launch_bounds__(256) void zero_f(float* __restrict__ p)
{
  int idx = blockIdx.x * 256 + threadIdx.x;
  ((float4*)p)[idx] = make_float4(0.f, 0.f, 0.f, 0.f);
}

// ---------------------------------------------------------------------------
// Pack weights W[K,N] (batch via blockIdx.y) into MFMA B-fragment order:
// frag(nblk,kblk) at ((nblk*(K/32)+kblk)*64+lane)*8; lo==nullptr -> hi only.
// ---------------------------------------------------------------------------
__global__ __launch_bounds__(256) void pack_wt(
    const float* __restrict__ W, ushort_t* __restrict__ hi,
    ushort_t* __restrict__ lo, int K, int N)
{
  int gid = blockIdx.x * 256 + threadIdx.x;   // [0, N*K/8)
  int lane = gid & 63;
  int kbc = K >> 5;
  int kblk = (gid >> 6) % kbc;
  int nblk = (gid >> 6) / kbc;
  size_t b = (size_t)blockIdx.y * K * N;
  int col = nblk * 16 + (lane & 15);
  int krow = kblk * 32 + (lane >> 4) * 8;
  ushort_t h[8] __attribute__((aligned(16)));
  ushort_t l[8] __attribute__((aligned(16)));
#pragma unroll
  for (int e = 0; e < 8; ++e) {
    float v = W[b + (size_t)(krow + e) * N + col];
    h[e] = f2bf(v);
    l[e] = f2bf(v - bf2f(h[e]));
  }
  *(uint4*)&hi[b + (size_t)gid * 8] = *(uint4*)h;
  if (lo) *(uint4*)&lo[b + (size_t)gid * 8] = *(uint4*)l;
}

// ---------------------------------------------------------------------------
// Fused h-GEMM: h = x@Wg (single-pass bf16), epilogue writes Bpack (B-frag
// order) + atomic s1/s2 dots. h never materialized in fp32.
// Block 128M x 64N, 4 waves 64x32; A via double-buffered LDS w/ register
// prefetch (global latency overlaps MFMA); B-frags direct from packed Wg (L2).
// Grid (N/64=4, M/128=64, heads=2). K=512 -> 16 k-steps.
// ---------------------------------------------------------------------------
__global__ __launch_bounds__(256, 2) void gemm_h(
    const ushort_t* __restrict__ xb, const ushort_t* __restrict__ Wgp,
    const float* __restrict__ a1, const float* __restrict__ a2,
    ushort_t* __restrict__ Bpack, float* __restrict__ s1,
    float* __restrict__ s2)
{
  __shared__ ushort_t Ab[2][128][40];
  const int t = threadIdx.x;
  const int head = blockIdx.z;
  const int m0 = blockIdx.y * 128;
  const int n0 = blockIdx.x * 64;
  const int wave = t >> 6;
  const int wm = (wave & 1) * 64, wn = (wave >> 1) * 32;
  const int l16 = t & 15, quad = (t >> 4) & 3, l63 = t & 63;
  const int sr = t >> 1, sp = (t & 1) * 16;
  const ushort_t* arow_g = xb + (size_t)(m0 + sr) * 512 + sp;
  const ushort_t* bp = Wgp + (size_t)head * 256 * 512;  // per-head packed N*K
  const int nb0 = (n0 + wn) >> 4;

  f32x4 acc[4][2];
#pragma unroll
  for (int i = 0; i < 4; ++i)
#pragma unroll
    for (int j = 0; j < 2; ++j) acc[i][j] = (f32x4){0.f, 0.f, 0.f, 0.f};

  uint4 r0, r1;
  r0 = *(const uint4*)(arow_g);
  r1 = *(const uint4*)(arow_g + 8);
  *(uint4*)&Ab[0][sr][sp] = r0;
  *(uint4*)&Ab[0][sr][sp + 8] = r1;
  __syncthreads();

  for (int kb = 0; kb < 16; ++kb) {
    const int cur = kb & 1, nxt = cur ^ 1;
    if (kb < 15) {
      const ushort_t* p = arow_g + (kb + 1) * 32;
      r0 = *(const uint4*)p;
      r1 = *(const uint4*)(p + 8);
    }
    bf16x8 Bf[2];
#pragma unroll
    for (int nt = 0; nt < 2; ++nt)
      Bf[nt] = *(const bf16x8*)&bp[(((size_t)(nb0 + nt) * 16 + kb) * 64 + l63) * 8];
    bf16x8 Af[4];
#pragma unroll
    for (int mt = 0; mt < 4; ++mt)
      Af[mt] = *(const bf16x8*)&Ab[cur][wm + mt * 16 + l16][quad * 8];
#pragma unroll
    for (int mt = 0; mt < 4; ++mt)
#pragma unroll
      for (int nt = 0; nt < 2; ++nt)
        acc[mt][nt] = __builtin_amdgcn_mfma_f32_16x16x32_bf16(
            Af[mt], Bf[nt], acc[mt][nt], 0, 0, 0);
    if (kb < 15) {
      *(uint4*)&Ab[nxt][sr][sp] = r0;
      *(uint4*)&Ab[nxt][sr][sp + 8] = r1;
    }
    __syncthreads();
  }

  // ---- epilogue 1: write Bpack in B-fragment order (bf16) ----
#pragma unroll
  for (int mt = 0; mt < 4; ++mt)
#pragma unroll
    for (int nt = 0; nt < 2; ++nt)
#pragma unroll
      for (int rg = 0; rg < 4; ++rg) {
        int j = m0 + wm + mt * 16 + quad * 4 + rg;
        int c = n0 + wn + nt * 16 + l16;
        int kblk = j >> 5;
        int laneb = ((j >> 3) & 3) * 16 + (c & 15);
        int e = j & 7;
        Bpack[(((size_t)head * 256 + kblk) * 16 + (c >> 4)) * 512 + laneb * 8 + e] =
            f2bf(acc[mt][nt][rg]);
      }
  // ---- epilogue 2: s1/s2 partial dots, shuffle-reduced over 16 cols ----
  float a1v[2], a2v[2];
#pragma unroll
  for (int nt = 0; nt < 2; ++nt) {
    int c = n0 + wn + nt * 16 + l16;
    a1v[nt] = a1[head * 256 + c];
    a2v[nt] = a2[head * 256 + c];
  }
#pragma unroll
  for (int mt = 0; mt < 4; ++mt)
#pragma unroll
    for (int rg = 0; rg < 4; ++rg) {
      float p1 = acc[mt][0][rg] * a1v[0] + acc[mt][1][rg] * a1v[1];
      float p2 = acc[mt][0][rg] * a2v[0] + acc[mt][1][rg] * a2v[1];
      p1 += __shfl_xor(p1, 1); p2 += __shfl_xor(p2, 1);
      p1 += __shfl_xor(p1, 2); p2 += __shfl_xor(p2, 2);
      p1 += __shfl_xor(p1, 4); p2 += __shfl_xor(p2, 4);
      p1 += __shfl_xor(p1, 8); p2 += __shfl_xor(p2, 8);
      if (l16 == 0) {
        int row = m0 + wm + mt * 16 + quad * 4 + rg;
        atomicAdd(&s1[head * 8192 + row], p1);
        atomicAdd(&s2[head * 8192 + row], p2);
      }
    }
}

// ---------------------------------------------------------------------------
// Pipelined split-bf16 MLP GEMM: C = lrelu(A[M,K]@W + bias), 3-pass hi/lo.
// A hi/lo via double-buffered LDS with register prefetch; B packed hi/lo
// frags direct from global (L2-resident weights). Block 128x64, 4 waves.
// ---------------------------------------------------------------------------
__global__ __launch_bounds__(256, 2) void gemm_mlp(
    const ushort_t* __restrict__ Ahi, const ushort_t* __restrict__ Alo,
    const ushort_t* __restrict__ Bph, const ushort_t* __restrict__ Bpl,
    const float* __restrict__ bias, float* __restrict__ Cf,
    ushort_t* __restrict__ Chi, ushort_t* __restrict__ Clo,
    int M, int N, int K, float slope)
{
  __shared__ ushort_t Ah[2][128][40], Al[2][128][40];
  const int kbc = K >> 5;
  const int t = threadIdx.x;
  const int m0 = blockIdx.y * 128;
  const int n0 = blockIdx.x * 64;
  const int wave = t >> 6;
  const int wm = (wave & 1) * 64, wn = (wave >> 1) * 32;
  const int l16 = t & 15, quad = (t >> 4) & 3, l63 = t & 63;
  const int sr = t >> 1, sp = (t & 1) * 16;
  const ushort_t* ah_g = Ahi + (size_t)(m0 + sr) * K + sp;
  const ushort_t* al_g = Alo + (size_t)(m0 + sr) * K + sp;
  const int nb0 = (n0 + wn) >> 4;

  f32x4 acc[4][2];
#pragma unroll
  for (int i = 0; i < 4; ++i)
#pragma unroll
    for (int j = 0; j < 2; ++j) acc[i][j] = (f32x4){0.f, 0.f, 0.f, 0.f};

  uint4 rh0, rh1, rl0, rl1;
  rh0 = *(const uint4*)(ah_g);
  rh1 = *(const uint4*)(ah_g + 8);
  rl0 = *(const uint4*)(al_g);
  rl1 = *(const uint4*)(al_g + 8);
  *(uint4*)&Ah[0][sr][sp] = rh0;
  *(uint4*)&Ah[0][sr][sp + 8] = rh1;
  *(uint4*)&Al[0][sr][sp] = rl0;
  *(uint4*)&Al[0][sr][sp + 8] = rl1;
  __syncthreads();

  for (int kb = 0; kb < kbc; ++kb) {
    const int cur = kb & 1, nxt = cur ^ 1;
    if (kb + 1 < kbc) {
      const ushort_t* ph = ah_g + (kb + 1) * 32;
      const ushort_t* plo = al_g + (kb + 1) * 32;
      rh0 = *(const uint4*)ph;
      rh1 = *(const uint4*)(ph + 8);
      rl0 = *(const uint4*)plo;
      rl1 = *(const uint4*)(plo + 8);
    }
    bf16x8 bh[2], bl[2];
#pragma unroll
    for (int nt = 0; nt < 2; ++nt) {
      size_t o = (((size_t)(nb0 + nt) * kbc + kb) * 64 + l63) * 8;
      bh[nt] = *(const bf16x8*)&Bph[o];
      bl[nt] = *(const bf16x8*)&Bpl[o];
    }
    bf16x8 afh[4], afl[4];
#pragma unroll
    for (int mt = 0; mt < 4; ++mt) {
      afh[mt] = *(const bf16x8*)&Ah[cur][wm + mt * 16 + l16][quad * 8];
      afl[mt] = *(const bf16x8*)&Al[cur][wm + mt * 16 + l16][quad * 8];
    }
#pragma unroll
    for (int mt = 0; mt < 4; ++mt)
#pragma unroll
      for (int nt = 0; nt < 2; ++nt) {
        acc[mt][nt] = __builtin_amdgcn_mfma_f32_16x16x32_bf16(afh[mt], bh[nt], acc[mt][nt], 0, 0, 0);
        acc[mt][nt] = __builtin_amdgcn_mfma_f32_16x16x32_bf16(afh[mt], bl[nt], acc[mt][nt], 0, 0, 0);
        acc[mt][nt] = __builtin_amdgcn_mfma_f32_16x16x32_bf16(afl[mt], bh[nt], acc[mt][nt], 0, 0, 0);
      }
    if (kb + 1 < kbc) {
      *(uint4*)&Ah[nxt][sr][sp] = rh0;
      *(uint4*)&Ah[nxt][sr][sp + 8] = rh1;
      *(uint4*)&Al[nxt][sr][sp] = rl0;
      *(uint4*)&Al[nxt][sr][sp + 8] = rl1;
    }
    __syncthreads();
  }

#pragma unroll
  for (int mt = 0; mt < 4; ++mt)
#pragma unroll
    for (int nt = 0; nt < 2; ++nt)
#pragma unroll
      for (int rg = 0; rg < 4; ++rg) {
        int m = m0 + wm + mt * 16 + quad * 4 + rg;
        int n = n0 + wn + nt * 16 + l16;
        float v = lrelu(acc[mt][nt][rg] + bias[n], slope);
        size_t o = (size_t)m * N + n;
        if (Cf) Cf[o] = v;
        if (Chi) {
          ushort_t h = f2bf(v);
          Chi[o] = h; Clo[o] = f2bf(v - bf2f(h));
        }
      }
}

// ---------------------------------------------------------------------------
// MFMA attention (R7-best, frozen): adj read once per block by generator
// threads, W exchanged via double-buffered LDS in A-frag order, B-frags from
// L2-resident Bpack, lgkm-only barrier, gen in MFMA shadow.
// ---------------------------------------------------------------------------
__global__ __launch_bounds__(256, 2) void attn_mfma6(
    const ushort_t* __restrict__ Bpack, const float* __restrict__ s1g,
    const float* __restrict__ s2g, const int* __restrict__ adj,
    ushort_t* __restrict__ pacc, float* __restrict__ pl)
{
  __shared__ ushort_t Wlds[2][2][4][64][8];   // [buf][head][mt][lane][8]
  const int t = threadIdx.x;
  const int i0 = blockIdx.x * 64;
  const int js = blockIdx.y;
  const int kbase = js * 2048;
  const int wr = t >> 2, kq = t & 3;
  const int glane = kq * 16 + (wr & 15);
  const int gmt = wr >> 4;
  const float s1v0 = s1g[i0 + wr];
  const float s1v1 = s1g[8192 + i0 + wr];
  const int wave = t >> 6, head = wave >> 1, nh = wave & 1;
  const int l16 = t & 15, quad = (t >> 4) & 3;
  const int l63 = t & 63;
  f32x4 acc[4][8];
#pragma unroll
  for (int m = 0; m < 4; ++m)
#pragma unroll
    for (int n = 0; n < 8; ++n) acc[m][n] = (f32x4){0.f, 0.f, 0.f, 0.f};
  float rs0 = 0.f, rs1 = 0.f;

  const int* arow = adj + (size_t)(i0 + wr) * 8192;
  int4 pa0, pa1;
  float4 p20a, p20b, p21a, p21b;

  auto fetch = [&](int kk) {
    pa0 = *(const int4*)&arow[kk];
    pa1 = *(const int4*)&arow[kk + 4];
    p20a = *(const float4*)&s2g[kk];
    p20b = *(const float4*)&s2g[kk + 4];
    p21a = *(const float4*)&s2g[8192 + kk];
    p21b = *(const float4*)&s2g[8192 + kk + 4];
  };
  auto gen = [&](int buf) {
    int am[8] = {pa0.x, pa0.y, pa0.z, pa0.w, pa1.x, pa1.y, pa1.z, pa1.w};
    float s20[8] = {p20a.x, p20a.y, p20a.z, p20a.w, p20b.x, p20b.y, p20b.z, p20b.w};
    float s21[8] = {p21a.x, p21a.y, p21a.z, p21a.w, p21b.x, p21b.y, p21b.z, p21b.w};
    ushort_t w0[8] __attribute__((aligned(16)));
    ushort_t w1[8] __attribute__((aligned(16)));
#pragma unroll
    for (int e = 0; e < 8; ++e) {
      float e0 = s1v0 + s20[e];
      float e1 = s1v1 + s21[e];
      e0 = fmaxf(e0, 0.f) + ALPHA * fminf(e0, 0.f);
      e1 = fmaxf(e1, 0.f) + ALPHA * fminf(e1, 0.f);
      float v0 = am[e] > 0 ? __expf(e0) : 0.f;
      float v1 = am[e] > 0 ? __expf(e1) : 0.f;
      rs0 += v0; rs1 += v1;
      w0[e] = f2bf(v0); w1[e] = f2bf(v1);
    }
    *(uint4*)&Wlds[buf][0][gmt][glane][0] = *(uint4*)w0;
    *(uint4*)&Wlds[buf][1][gmt][glane][0] = *(uint4*)w1;
  };

  fetch(kbase + kq * 8);
  gen(0);
  fetch(kbase + 32 + kq * 8);
  ASM_BARRIER();

  for (int kt = 0; kt < 64; ++kt) {
    const int cur = kt & 1, nxt = cur ^ 1;
    const int kblk = js * 64 + kt;
    const ushort_t* bb =
        Bpack + ((((size_t)head * 256 + kblk) * 16 + nh * 8) * 64 + l63) * 8;
    bf16x8 Bf[8];
#pragma unroll
    for (int nt = 0; nt < 8; ++nt)
      Bf[nt] = *(const bf16x8*)&bb[nt * 512];
    bf16x8 Af[4];
#pragma unroll
    for (int mt = 0; mt < 4; ++mt)
      Af[mt] = *(const bf16x8*)&Wlds[cur][head][mt][l63][0];
#pragma unroll
    for (int mt = 0; mt < 4; ++mt)
#pragma unroll
      for (int nt = 0; nt < 8; ++nt)
        acc[mt][nt] = __builtin_amdgcn_mfma_f32_16x16x32_bf16(
            Af[mt], Bf[nt], acc[mt][nt], 0, 0, 0);
    if (kt < 63) {
      gen(nxt);
      if (kt < 62) fetch(kbase + (kt + 2) * 32 + kq * 8);
    }
    ASM_BARRIER();
  }

  rs0 += __shfl_xor(rs0, 1); rs0 += __shfl_xor(rs0, 2);
  rs1 += __shfl_xor(rs1, 1); rs1 += __shfl_xor(rs1, 2);
  if (kq == 0) {
    pl[((size_t)js * 2 + 0) * 8192 + i0 + wr] = rs0;
    pl[((size_t)js * 2 + 1) * 8192 + i0 + wr] = rs1;
  }
  const int n0 = nh * 128;
#pragma unroll
  for (int mt = 0; mt < 4; ++mt)
#pragma unroll
    for (int nt = 0; nt < 8; ++nt)
#pragma unroll
      for (int rg = 0; rg < 4; ++rg) {
        int row = i0 + mt * 16 + quad * 4 + rg;
        int col = n0 + nt * 16 + l16;
        pacc[(((size_t)js * 2 + head) * 8192 + row) * 256 + col] =
            f2bf(acc[mt][nt][rg]);
      }
}

// ---------------------------------------------------------------------------
// Finalize: sum j-parts, /l, lrelu, l2-norm, +bias, head-mean; emits embed
// directly as hi/lo bf16 split (llm cols split inline) — no fp32 embed.
// ---------------------------------------------------------------------------
__global__ __launch_bounds__(256) void attn_finalize(
    const ushort_t* __restrict__ pacc, const float* __restrict__ pl,
    const float* __restrict__ bg, const float* __restrict__ llm,
    ushort_t* __restrict__ ehi, ushort_t* __restrict__ elo)
{
  __shared__ float red[8];
  const int r = blockIdx.x;
  const int t = threadIdx.x;
  const int wv = t >> 6, lane = t & 63;
  // llm part: cols [0,512) split
#pragma unroll
  for (int half = 0; half < 2; ++half) {
    float lv = llm[(size_t)r * 512 + half * 256 + t];
    ushort_t h = f2bf(lv);
    ehi[(size_t)r * 768 + half * 256 + t] = h;
    elo[(size_t)r * 768 + half * 256 + t] = f2bf(lv - bf2f(h));
  }
  float o[2];
#pragma unroll
  for (int hh = 0; hh < 2; ++hh) {
    float num = 0.f, l = 0.f;
#pragma unroll
    for (int js = 0; js < 4; ++js) {
      num += bf2f(pacc[(((size_t)js * 2 + hh) * 8192 + r) * 256 + t]);
      l += pl[((size_t)js * 2 + hh) * 8192 + r];
    }
    o[hh] = lrelu(num / l, ALPHA);
  }
  float v0 = o[0] * o[0], v1 = o[1] * o[1];
  for (int off = 32; off > 0; off >>= 1) {
    v0 += __shfl_xor(v0, off);
    v1 += __shfl_xor(v1, off);
  }
  if (lane == 0) { red[wv] = v0; red[4 + wv] = v1; }
  __syncthreads();
  float n0 = fmaxf(sqrtf(red[0] + red[1] + red[2] + red[3]), 1e-12f);
  float n1 = fmaxf(sqrtf(red[4] + red[5] + red[6] + red[7]), 1e-12f);
  float val = 0.5f * (o[0] / n0 + bg[t] + o[1] / n1 + bg[256 + t]);
  ushort_t h = f2bf(val);
  ehi[(size_t)r * 768 + 512 + t] = h;
  elo[(size_t)r * 768 + 512 + t] = f2bf(val - bf2f(h));
}

// ---------------------------------------------------------------------------
__global__ __launch_bounds__(256) void pred_kernel(
    const float* __restrict__ z2, const int* __restrict__ ts,
    float* __restrict__ out, int E)
{
  const int gw = (blockIdx.x * 256 + threadIdx.x) >> 6;
  const int lane = threadIdx.x & 63;
  if (gw >= E) return;
  const int a = ts[gw * 2], b = ts[gw * 2 + 1];
  float4 va = ((const float4*)(z2 + (size_t)a * 256))[lane];
  float4 vb = ((const float4*)(z2 + (size_t)b * 256))[lane];
  float p = va.x * vb.x + va.y * vb.y + va.z * vb.z + va.w * vb.w;
  for (int off = 32; off > 0; off >>= 1) p += __shfl_xor(p, off);
  if (lane == 0) out[gw] = p;
}

// ---------------------------------------------------------------------------
extern "C" void kernel_launch(void* const* d_in, const int* in_sizes, int n_in,
                              void* d_out, int out_size, void* d_ws, size_t ws_size,
                              hipStream_t stream) {
  const float* x   = (const float*)d_in[0];
  const int*   adj = (const int*)d_in[1];
  const int*   ts  = (const int*)d_in[2];
  const float* llm = (const float*)d_in[3];
  const float* Wg  = (const float*)d_in[4];
  const float* a1  = (const float*)d_in[5];
  const float* a2  = (const float*)d_in[6];
  const float* bg  = (const float*)d_in[7];
  const float* W1  = (const float*)d_in[8];
  const float* b1  = (const float*)d_in[9];
  const float* W2  = (const float*)d_in[10];
  const float* b2  = (const float*)d_in[11];
  float* out = (float*)d_out;
  float* ws  = (float*)d_ws;
  const int E = in_sizes[2] / 2;

  // ---- workspace layout (float words) ----
  ushort_t* xb    = (ushort_t*)(ws + 0);            //  8192x512 bf16
  ushort_t* Wgp   = (ushort_t*)(ws + 2097152);      //  2x512x256
  ushort_t* W1ph  = (ushort_t*)(ws + 2228224);      //  768x512
  ushort_t* W1pl  = (ushort_t*)(ws + 2424832);
  ushort_t* W2ph  = (ushort_t*)(ws + 2621440);      //  512x256
  ushort_t* W2pl  = (ushort_t*)(ws + 2686976);
  ushort_t* Bpack = (ushort_t*)(ws + 2752512);      //  2x8192x256
  float*    s1    = ws + 4849664;                   //  2x8192
  float*    s2    = ws + 4866048;
  float*    pl    = ws + 4882432;                   //  8x8192
  ushort_t* pacc  = (ushort_t*)(ws + 4947968);      //  8x8192x256
  ushort_t* ehi   = (ushort_t*)(ws + 13336576);     //  8192x768
  ushort_t* elo   = (ushort_t*)(ws + 16482304);
  ushort_t* z1hi  = (ushort_t*)(ws + 19628032);     //  8192x512
  ushort_t* z1lo  = (ushort_t*)(ws + 21725184);
  float*    z2    = ws + 23822336;                  //  8192x256 f32

  // 1. prep: casts, weight packing, s-zero
  tobf<<<4096, 256, 0, stream>>>(x, xb);
  pack_wt<<<dim3(64, 2), 256, 0, stream>>>(Wg, Wgp, nullptr, 512, 256);
  pack_wt<<<dim3(192, 1), 256, 0, stream>>>(W1, W1ph, W1pl, 768, 512);
  pack_wt<<<dim3(64, 1), 256, 0, stream>>>(W2, W2ph, W2pl, 512, 256);
  zero_f<<<32, 256, 0, stream>>>(s1);   // covers s1 and s2 (contiguous)
  // 2. fused h-GEMM -> Bpack + s1/s2 (hbuf never materialized)
  gemm_h<<<dim3(4, 64, 2), 256, 0, stream>>>(xb, Wgp, a1, a2, Bpack, s1, s2);
  // 3. MFMA attention partials (R7-best, frozen)
  attn_mfma6<<<dim3(128, 4), 256, 0, stream>>>(Bpack, s1, s2, adj, pacc, pl);
  // 4. finalize -> embed emitted directly as hi/lo split (llm inline)
  attn_finalize<<<8192, 256, 0, stream>>>(pacc, pl, bg, llm, ehi, elo);
  // 5. z1 = LR(embed @ W1 + b1) -> hi/lo
  gemm_mlp<<<dim3(8, 64), 256, 0, stream>>>(
      ehi, elo, W1ph, W1pl, b1, nullptr, z1hi, z1lo, 8192, 512, 768, MLP_SLOPE);
  // 6. z2 = LR(z1 @ W2 + b2) -> fp32
  gemm_mlp<<<dim3(4, 64), 256, 0, stream>>>(
      z1hi, z1lo, W2ph, W2pl, b2, z2, nullptr, nullptr, 8192, 256, 512, MLP_SLOPE);
  // 7. edge dots
  pred_kernel<<<(E * 64 + 255) / 256, 256, 0, stream>>>(z2, ts, out, E);
}

// Round 10
// 582.404 us; speedup vs baseline: 1.2890x; 1.0207x over previous
//
#include <hip/hip_runtime.h>
#include <hip/hip_bf16.h>
#include <cstdint>
#include <cstddef>

#define ALPHA 0.2f
#define MLP_SLOPE 0.01f

typedef short bf16x8 __attribute__((ext_vector_type(8)));
typedef float f32x4 __attribute__((ext_vector_type(4)));
typedef unsigned short ushort_t;

// raw barrier: syncs LDS exchange WITHOUT draining vmcnt (global prefetches
// stay in flight across it).
#define ASM_BARRIER() __asm__ __volatile__("s_waitcnt lgkmcnt(0)\n\ts_barrier" ::: "memory")

__device__ __forceinline__ float lrelu(float x, float s) { return x > 0.f ? x : x * s; }
__device__ __forceinline__ ushort_t f2bf(float x) {
  __hip_bfloat16 h = __float2bfloat16(x);
  return *reinterpret_cast<ushort_t*>(&h);
}
__device__ __forceinline__ float bf2f(ushort_t u) {
  union { unsigned int i; float f; } v; v.i = ((unsigned int)u) << 16; return v.f;
}

// ---------------------------------------------------------------------------
// cast fp32 -> bf16, 4 elems/thread
// ---------------------------------------------------------------------------
__global__ __launch_bounds__(256) void tobf(
    const float* __restrict__ in, ushort_t* __restrict__ outp)
{
  int idx = blockIdx.x * 256 + threadIdx.x;
  float4 v = ((const float4*)in)[idx];
  ushort4 h;
  h.x = f2bf(v.x); h.y = f2bf(v.y); h.z = f2bf(v.z); h.w = f2bf(v.w);
  ((ushort4*)outp)[idx] = h;
}

// ---------------------------------------------------------------------------
// zero a float buffer (s1/s2 init for atomics)
// ---------------------------------------------------------------------------
__global__ __launch_bounds__(256) void zero_f(float* __restrict__ p)
{
  int idx = blockIdx.x * 256 + threadIdx.x;
  ((float4*)p)[idx] = make_float4(0.f, 0.f, 0.f, 0.f);
}

// ---------------------------------------------------------------------------
// Pack weights W[K,N] (batch via blockIdx.y) into MFMA B-fragment order:
// frag(nblk,kblk) at ((nblk*(K/32)+kblk)*64+lane)*8; lo==nullptr -> hi only.
// ---------------------------------------------------------------------------
__global__ __launch_bounds__(256) void pack_wt(
    const float* __restrict__ W, ushort_t* __restrict__ hi,
    ushort_t* __restrict__ lo, int K, int N)
{
  int gid = blockIdx.x * 256 + threadIdx.x;   // [0, N*K/8)
  int lane = gid & 63;
  int kbc = K >> 5;
  int kblk = (gid >> 6) % kbc;
  int nblk = (gid >> 6) / kbc;
  size_t b = (size_t)blockIdx.y * K * N;
  int col = nblk * 16 + (lane & 15);
  int krow = kblk * 32 + (lane >> 4) * 8;
  ushort_t h[8] __attribute__((aligned(16)));
  ushort_t l[8] __attribute__((aligned(16)));
#pragma unroll
  for (int e = 0; e < 8; ++e) {
    float v = W[b + (size_t)(krow + e) * N + col];
    h[e] = f2bf(v);
    l[e] = f2bf(v - bf2f(h[e]));
  }
  *(uint4*)&hi[b + (size_t)gid * 8] = *(uint4*)h;
  if (lo) *(uint4*)&lo[b + (size_t)gid * 8] = *(uint4*)l;
}

// ---------------------------------------------------------------------------
// Fused h-GEMM: h = x@Wg (single-pass bf16), epilogue writes Bpack (B-frag
// order) + atomic s1/s2 dots. h never materialized in fp32.  (R9, frozen)
// ---------------------------------------------------------------------------
__global__ __launch_bounds__(256, 2) void gemm_h(
    const ushort_t* __restrict__ xb, const ushort_t* __restrict__ Wgp,
    const float* __restrict__ a1, const float* __restrict__ a2,
    ushort_t* __restrict__ Bpack, float* __restrict__ s1,
    float* __restrict__ s2)
{
  __shared__ ushort_t Ab[2][128][40];
  const int t = threadIdx.x;
  const int head = blockIdx.z;
  const int m0 = blockIdx.y * 128;
  const int n0 = blockIdx.x * 64;
  const int wave = t >> 6;
  const int wm = (wave & 1) * 64, wn = (wave >> 1) * 32;
  const int l16 = t & 15, quad = (t >> 4) & 3, l63 = t & 63;
  const int sr = t >> 1, sp = (t & 1) * 16;
  const ushort_t* arow_g = xb + (size_t)(m0 + sr) * 512 + sp;
  const ushort_t* bp = Wgp + (size_t)head * 256 * 512;
  const int nb0 = (n0 + wn) >> 4;

  f32x4 acc[4][2];
#pragma unroll
  for (int i = 0; i < 4; ++i)
#pragma unroll
    for (int j = 0; j < 2; ++j) acc[i][j] = (f32x4){0.f, 0.f, 0.f, 0.f};

  uint4 r0, r1;
  r0 = *(const uint4*)(arow_g);
  r1 = *(const uint4*)(arow_g + 8);
  *(uint4*)&Ab[0][sr][sp] = r0;
  *(uint4*)&Ab[0][sr][sp + 8] = r1;
  __syncthreads();

  for (int kb = 0; kb < 16; ++kb) {
    const int cur = kb & 1, nxt = cur ^ 1;
    if (kb < 15) {
      const ushort_t* p = arow_g + (kb + 1) * 32;
      r0 = *(const uint4*)p;
      r1 = *(const uint4*)(p + 8);
    }
    bf16x8 Bf[2];
#pragma unroll
    for (int nt = 0; nt < 2; ++nt)
      Bf[nt] = *(const bf16x8*)&bp[(((size_t)(nb0 + nt) * 16 + kb) * 64 + l63) * 8];
    bf16x8 Af[4];
#pragma unroll
    for (int mt = 0; mt < 4; ++mt)
      Af[mt] = *(const bf16x8*)&Ab[cur][wm + mt * 16 + l16][quad * 8];
#pragma unroll
    for (int mt = 0; mt < 4; ++mt)
#pragma unroll
      for (int nt = 0; nt < 2; ++nt)
        acc[mt][nt] = __builtin_amdgcn_mfma_f32_16x16x32_bf16(
            Af[mt], Bf[nt], acc[mt][nt], 0, 0, 0);
    if (kb < 15) {
      *(uint4*)&Ab[nxt][sr][sp] = r0;
      *(uint4*)&Ab[nxt][sr][sp + 8] = r1;
    }
    __syncthreads();
  }

  // ---- epilogue 1: write Bpack in B-fragment order (bf16) ----
#pragma unroll
  for (int mt = 0; mt < 4; ++mt)
#pragma unroll
    for (int nt = 0; nt < 2; ++nt)
#pragma unroll
      for (int rg = 0; rg < 4; ++rg) {
        int j = m0 + wm + mt * 16 + quad * 4 + rg;
        int c = n0 + wn + nt * 16 + l16;
        int kblk = j >> 5;
        int laneb = ((j >> 3) & 3) * 16 + (c & 15);
        int e = j & 7;
        Bpack[(((size_t)head * 256 + kblk) * 16 + (c >> 4)) * 512 + laneb * 8 + e] =
            f2bf(acc[mt][nt][rg]);
      }
  // ---- epilogue 2: s1/s2 partial dots, shuffle-reduced over 16 cols ----
  float a1v[2], a2v[2];
#pragma unroll
  for (int nt = 0; nt < 2; ++nt) {
    int c = n0 + wn + nt * 16 + l16;
    a1v[nt] = a1[head * 256 + c];
    a2v[nt] = a2[head * 256 + c];
  }
#pragma unroll
  for (int mt = 0; mt < 4; ++mt)
#pragma unroll
    for (int rg = 0; rg < 4; ++rg) {
      float p1 = acc[mt][0][rg] * a1v[0] + acc[mt][1][rg] * a1v[1];
      float p2 = acc[mt][0][rg] * a2v[0] + acc[mt][1][rg] * a2v[1];
      p1 += __shfl_xor(p1, 1); p2 += __shfl_xor(p2, 1);
      p1 += __shfl_xor(p1, 2); p2 += __shfl_xor(p2, 2);
      p1 += __shfl_xor(p1, 4); p2 += __shfl_xor(p2, 4);
      p1 += __shfl_xor(p1, 8); p2 += __shfl_xor(p2, 8);
      if (l16 == 0) {
        int row = m0 + wm + mt * 16 + quad * 4 + rg;
        atomicAdd(&s1[head * 8192 + row], p1);
        atomicAdd(&s2[head * 8192 + row], p2);
      }
    }
}

// ---------------------------------------------------------------------------
// Pipelined split-bf16 MLP GEMM (R9, frozen).
// ---------------------------------------------------------------------------
__global__ __launch_bounds__(256, 2) void gemm_mlp(
    const ushort_t* __restrict__ Ahi, const ushort_t* __restrict__ Alo,
    const ushort_t* __restrict__ Bph, const ushort_t* __restrict__ Bpl,
    const float* __restrict__ bias, float* __restrict__ Cf,
    ushort_t* __restrict__ Chi, ushort_t* __restrict__ Clo,
    int M, int N, int K, float slope)
{
  __shared__ ushort_t Ah[2][128][40], Al[2][128][40];
  const int kbc = K >> 5;
  const int t = threadIdx.x;
  const int m0 = blockIdx.y * 128;
  const int n0 = blockIdx.x * 64;
  const int wave = t >> 6;
  const int wm = (wave & 1) * 64, wn = (wave >> 1) * 32;
  const int l16 = t & 15, quad = (t >> 4) & 3, l63 = t & 63;
  const int sr = t >> 1, sp = (t & 1) * 16;
  const ushort_t* ah_g = Ahi + (size_t)(m0 + sr) * K + sp;
  const ushort_t* al_g = Alo + (size_t)(m0 + sr) * K + sp;
  const int nb0 = (n0 + wn) >> 4;

  f32x4 acc[4][2];
#pragma unroll
  for (int i = 0; i < 4; ++i)
#pragma unroll
    for (int j = 0; j < 2; ++j) acc[i][j] = (f32x4){0.f, 0.f, 0.f, 0.f};

  uint4 rh0, rh1, rl0, rl1;
  rh0 = *(const uint4*)(ah_g);
  rh1 = *(const uint4*)(ah_g + 8);
  rl0 = *(const uint4*)(al_g);
  rl1 = *(const uint4*)(al_g + 8);
  *(uint4*)&Ah[0][sr][sp] = rh0;
  *(uint4*)&Ah[0][sr][sp + 8] = rh1;
  *(uint4*)&Al[0][sr][sp] = rl0;
  *(uint4*)&Al[0][sr][sp + 8] = rl1;
  __syncthreads();

  for (int kb = 0; kb < kbc; ++kb) {
    const int cur = kb & 1, nxt = cur ^ 1;
    if (kb + 1 < kbc) {
      const ushort_t* ph = ah_g + (kb + 1) * 32;
      const ushort_t* plo = al_g + (kb + 1) * 32;
      rh0 = *(const uint4*)ph;
      rh1 = *(const uint4*)(ph + 8);
      rl0 = *(const uint4*)plo;
      rl1 = *(const uint4*)(plo + 8);
    }
    bf16x8 bh[2], bl[2];
#pragma unroll
    for (int nt = 0; nt < 2; ++nt) {
      size_t o = (((size_t)(nb0 + nt) * kbc + kb) * 64 + l63) * 8;
      bh[nt] = *(const bf16x8*)&Bph[o];
      bl[nt] = *(const bf16x8*)&Bpl[o];
    }
    bf16x8 afh[4], afl[4];
#pragma unroll
    for (int mt = 0; mt < 4; ++mt) {
      afh[mt] = *(const bf16x8*)&Ah[cur][wm + mt * 16 + l16][quad * 8];
      afl[mt] = *(const bf16x8*)&Al[cur][wm + mt * 16 + l16][quad * 8];
    }
#pragma unroll
    for (int mt = 0; mt < 4; ++mt)
#pragma unroll
      for (int nt = 0; nt < 2; ++nt) {
        acc[mt][nt] = __builtin_amdgcn_mfma_f32_16x16x32_bf16(afh[mt], bh[nt], acc[mt][nt], 0, 0, 0);
        acc[mt][nt] = __builtin_amdgcn_mfma_f32_16x16x32_bf16(afh[mt], bl[nt], acc[mt][nt], 0, 0, 0);
        acc[mt][nt] = __builtin_amdgcn_mfma_f32_16x16x32_bf16(afl[mt], bh[nt], acc[mt][nt], 0, 0, 0);
      }
    if (kb + 1 < kbc) {
      *(uint4*)&Ah[nxt][sr][sp] = rh0;
      *(uint4*)&Ah[nxt][sr][sp + 8] = rh1;
      *(uint4*)&Al[nxt][sr][sp] = rl0;
      *(uint4*)&Al[nxt][sr][sp + 8] = rl1;
    }
    __syncthreads();
  }

#pragma unroll
  for (int mt = 0; mt < 4; ++mt)
#pragma unroll
    for (int nt = 0; nt < 2; ++nt)
#pragma unroll
      for (int rg = 0; rg < 4; ++rg) {
        int m = m0 + wm + mt * 16 + quad * 4 + rg;
        int n = n0 + wn + nt * 16 + l16;
        float v = lrelu(acc[mt][nt][rg] + bias[n], slope);
        size_t o = (size_t)m * N + n;
        if (Cf) Cf[o] = v;
        if (Chi) {
          ushort_t h = f2bf(v);
          Chi[o] = h; Clo[o] = f2bf(v - bf2f(h));
        }
      }
}

// ---------------------------------------------------------------------------
// MFMA attention v8: 128-ROW, 512-THREAD blocks to halve Bpack L2 traffic.
// 8 waves = (head, n-half, row-group); the two row-group waves of a
// (head,nh) pair read the SAME Bf tile -> second hits L1 (tile 32KB = L1).
// Unique Bpack L2 reads halve vs v6. Grid 64x4 = 256 blocks = 1/CU, 8
// waves/CU (same occupancy as v6). Gen mapping: 512 thr cover 128 rows x
// 4 k-octets, both heads (16 exps/thread, same as v6). adj read once,
// coalesced. Double-buffered LDS W (32KB), lgkm-only barrier, gen in MFMA
// shadow, adj/s2 prefetched 2 steps ahead.
// ---------------------------------------------------------------------------
__global__ __launch_bounds__(512, 1) void attn_mfma8(
    const ushort_t* __restrict__ Bpack, const float* __restrict__ s1g,
    const float* __restrict__ s2g, const int* __restrict__ adj,
    ushort_t* __restrict__ pacc, float* __restrict__ pl)
{
  __shared__ ushort_t Wlds[2][2][8][64][8];   // [buf][head][mt8][lane][8]
  const int t = threadIdx.x;
  const int i0 = blockIdx.x * 128;
  const int js = blockIdx.y;
  const int kbase = js * 2048;
  // generator mapping: row wr (0..127), k-octet kq (0..3)
  const int wr = t >> 2, kq = t & 3;
  const int glane = kq * 16 + (wr & 15);
  const int gmt = wr >> 4;                    // 0..7
  const float s1v0 = s1g[i0 + wr];
  const float s1v1 = s1g[8192 + i0 + wr];
  // consumer mapping: wave = (head, nh, rowgrp)
  const int wave = t >> 6;
  const int head = wave >> 2, nh = (wave >> 1) & 1, rg2 = wave & 1;
  const int l16 = t & 15, quad = (t >> 4) & 3;
  const int l63 = t & 63;
  f32x4 acc[4][8];
#pragma unroll
  for (int m = 0; m < 4; ++m)
#pragma unroll
    for (int n = 0; n < 8; ++n) acc[m][n] = (f32x4){0.f, 0.f, 0.f, 0.f};
  float rs0 = 0.f, rs1 = 0.f;

  const int* arow = adj + (size_t)(i0 + wr) * 8192;
  int4 pa0, pa1;
  float4 p20a, p20b, p21a, p21b;

  auto fetch = [&](int kk) {
    pa0 = *(const int4*)&arow[kk];
    pa1 = *(const int4*)&arow[kk + 4];
    p20a = *(const float4*)&s2g[kk];
    p20b = *(const float4*)&s2g[kk + 4];
    p21a = *(const float4*)&s2g[8192 + kk];
    p21b = *(const float4*)&s2g[8192 + kk + 4];
  };
  auto gen = [&](int buf) {
    int am[8] = {pa0.x, pa0.y, pa0.z, pa0.w, pa1.x, pa1.y, pa1.z, pa1.w};
    float s20[8] = {p20a.x, p20a.y, p20a.z, p20a.w, p20b.x, p20b.y, p20b.z, p20b.w};
    float s21[8] = {p21a.x, p21a.y, p21a.z, p21a.w, p21b.x, p21b.y, p21b.z, p21b.w};
    ushort_t w0[8] __attribute__((aligned(16)));
    ushort_t w1[8] __attribute__((aligned(16)));
#pragma unroll
    for (int e = 0; e < 8; ++e) {
      float e0 = s1v0 + s20[e];
      float e1 = s1v1 + s21[e];
      e0 = fmaxf(e0, 0.f) + ALPHA * fminf(e0, 0.f);
      e1 = fmaxf(e1, 0.f) + ALPHA * fminf(e1, 0.f);
      float v0 = am[e] > 0 ? __expf(e0) : 0.f;
      float v1 = am[e] > 0 ? __expf(e1) : 0.f;
      rs0 += v0; rs1 += v1;
      w0[e] = f2bf(v0); w1[e] = f2bf(v1);
    }
    *(uint4*)&Wlds[buf][0][gmt][glane][0] = *(uint4*)w0;
    *(uint4*)&Wlds[buf][1][gmt][glane][0] = *(uint4*)w1;
  };

  fetch(kbase + kq * 8);
  gen(0);
  fetch(kbase + 32 + kq * 8);
  ASM_BARRIER();

  for (int kt = 0; kt < 64; ++kt) {
    const int cur = kt & 1, nxt = cur ^ 1;
    const int kblk = js * 64 + kt;
    const ushort_t* bb =
        Bpack + ((((size_t)head * 256 + kblk) * 16 + nh * 8) * 64 + l63) * 8;
    bf16x8 Bf[8];
#pragma unroll
    for (int nt = 0; nt < 8; ++nt)
      Bf[nt] = *(const bf16x8*)&bb[nt * 512];
    bf16x8 Af[4];
#pragma unroll
    for (int mt = 0; mt < 4; ++mt)
      Af[mt] = *(const bf16x8*)&Wlds[cur][head][rg2 * 4 + mt][l63][0];
#pragma unroll
    for (int mt = 0; mt < 4; ++mt)
#pragma unroll
      for (int nt = 0; nt < 8; ++nt)
        acc[mt][nt] = __builtin_amdgcn_mfma_f32_16x16x32_bf16(
            Af[mt], Bf[nt], acc[mt][nt], 0, 0, 0);
    if (kt < 63) {
      gen(nxt);
      if (kt < 62) fetch(kbase + (kt + 2) * 32 + kq * 8);
    }
    ASM_BARRIER();
  }

  // denominators: reduce across the 4 kq lanes of each row
  rs0 += __shfl_xor(rs0, 1); rs0 += __shfl_xor(rs0, 2);
  rs1 += __shfl_xor(rs1, 1); rs1 += __shfl_xor(rs1, 2);
  if (kq == 0) {
    pl[((size_t)js * 2 + 0) * 8192 + i0 + wr] = rs0;
    pl[((size_t)js * 2 + 1) * 8192 + i0 + wr] = rs1;
  }
  // store bf16 partial numerators
  const int n0 = nh * 128;
#pragma unroll
  for (int mt = 0; mt < 4; ++mt)
#pragma unroll
    for (int nt = 0; nt < 8; ++nt)
#pragma unroll
      for (int rg = 0; rg < 4; ++rg) {
        int row = i0 + rg2 * 64 + mt * 16 + quad * 4 + rg;
        int col = n0 + nt * 16 + l16;
        pacc[(((size_t)js * 2 + head) * 8192 + row) * 256 + col] =
            f2bf(acc[mt][nt][rg]);
      }
}

// ---------------------------------------------------------------------------
// Finalize (R9, frozen): emits embed directly as hi/lo bf16 split.
// ---------------------------------------------------------------------------
__global__ __launch_bounds__(256) void attn_finalize(
    const ushort_t* __restrict__ pacc, const float* __restrict__ pl,
    const float* __restrict__ bg, const float* __restrict__ llm,
    ushort_t* __restrict__ ehi, ushort_t* __restrict__ elo)
{
  __shared__ float red[8];
  const int r = blockIdx.x;
  const int t = threadIdx.x;
  const int wv = t >> 6, lane = t & 63;
#pragma unroll
  for (int half = 0; half < 2; ++half) {
    float lv = llm[(size_t)r * 512 + half * 256 + t];
    ushort_t h = f2bf(lv);
    ehi[(size_t)r * 768 + half * 256 + t] = h;
    elo[(size_t)r * 768 + half * 256 + t] = f2bf(lv - bf2f(h));
  }
  float o[2];
#pragma unroll
  for (int hh = 0; hh < 2; ++hh) {
    float num = 0.f, l = 0.f;
#pragma unroll
    for (int js = 0; js < 4; ++js) {
      num += bf2f(pacc[(((size_t)js * 2 + hh) * 8192 + r) * 256 + t]);
      l += pl[((size_t)js * 2 + hh) * 8192 + r];
    }
    o[hh] = lrelu(num / l, ALPHA);
  }
  float v0 = o[0] * o[0], v1 = o[1] * o[1];
  for (int off = 32; off > 0; off >>= 1) {
    v0 += __shfl_xor(v0, off);
    v1 += __shfl_xor(v1, off);
  }
  if (lane == 0) { red[wv] = v0; red[4 + wv] = v1; }
  __syncthreads();
  float n0 = fmaxf(sqrtf(red[0] + red[1] + red[2] + red[3]), 1e-12f);
  float n1 = fmaxf(sqrtf(red[4] + red[5] + red[6] + red[7]), 1e-12f);
  float val = 0.5f * (o[0] / n0 + bg[t] + o[1] / n1 + bg[256 + t]);
  ushort_t h = f2bf(val);
  ehi[(size_t)r * 768 + 512 + t] = h;
  elo[(size_t)r * 768 + 512 + t] = f2bf(val - bf2f(h));
}

// ---------------------------------------------------------------------------
__global__ __launch_bounds__(256) void pred_kernel(
    const float* __restrict__ z2, const int* __restrict__ ts,
    float* __restrict__ out, int E)
{
  const int gw = (blockIdx.x * 256 + threadIdx.x) >> 6;
  const int lane = threadIdx.x & 63;
  if (gw >= E) return;
  const int a = ts[gw * 2], b = ts[gw * 2 + 1];
  float4 va = ((const float4*)(z2 + (size_t)a * 256))[lane];
  float4 vb = ((const float4*)(z2 + (size_t)b * 256))[lane];
  float p = va.x * vb.x + va.y * vb.y + va.z * vb.z + va.w * vb.w;
  for (int off = 32; off > 0; off >>= 1) p += __shfl_xor(p, off);
  if (lane == 0) out[gw] = p;
}

// ---------------------------------------------------------------------------
extern "C" void kernel_launch(void* const* d_in, const int* in_sizes, int n_in,
                              void* d_out, int out_size, void* d_ws, size_t ws_size,
                              hipStream_t stream) {
  const float* x   = (const float*)d_in[0];
  const int*   adj = (const int*)d_in[1];
  const int*   ts  = (const int*)d_in[2];
  const float* llm = (const float*)d_in[3];
  const float* Wg  = (const float*)d_in[4];
  const float* a1  = (const float*)d_in[5];
  const float* a2  = (const float*)d_in[6];
  const float* bg  = (const float*)d_in[7];
  const float* W1  = (const float*)d_in[8];
  const float* b1  = (const float*)d_in[9];
  const float* W2  = (const float*)d_in[10];
  const float* b2  = (const float*)d_in[11];
  float* out = (float*)d_out;
  float* ws  = (float*)d_ws;
  const int E = in_sizes[2] / 2;

  // ---- workspace layout (float words) ----
  ushort_t* xb    = (ushort_t*)(ws + 0);            //  8192x512 bf16
  ushort_t* Wgp   = (ushort_t*)(ws + 2097152);      //  2x512x256
  ushort_t* W1ph  = (ushort_t*)(ws + 2228224);      //  768x512
  ushort_t* W1pl  = (ushort_t*)(ws + 2424832);
  ushort_t* W2ph  = (ushort_t*)(ws + 2621440);      //  512x256
  ushort_t* W2pl  = (ushort_t*)(ws + 2686976);
  ushort_t* Bpack = (ushort_t*)(ws + 2752512);      //  2x8192x256
  float*    s1    = ws + 4849664;                   //  2x8192
  float*    s2    = ws + 4866048;
  float*    pl    = ws + 4882432;                   //  8x8192
  ushort_t* pacc  = (ushort_t*)(ws + 4947968);      //  8x8192x256
  ushort_t* ehi   = (ushort_t*)(ws + 13336576);     //  8192x768
  ushort_t* elo   = (ushort_t*)(ws + 16482304);
  ushort_t* z1hi  = (ushort_t*)(ws + 19628032);     //  8192x512
  ushort_t* z1lo  = (ushort_t*)(ws + 21725184);
  float*    z2    = ws + 23822336;                  //  8192x256 f32

  // 1. prep: casts, weight packing, s-zero
  tobf<<<4096, 256, 0, stream>>>(x, xb);
  pack_wt<<<dim3(64, 2), 256, 0, stream>>>(Wg, Wgp, nullptr, 512, 256);
  pack_wt<<<dim3(192, 1), 256, 0, stream>>>(W1, W1ph, W1pl, 768, 512);
  pack_wt<<<dim3(64, 1), 256, 0, stream>>>(W2, W2ph, W2pl, 512, 256);
  zero_f<<<32, 256, 0, stream>>>(s1);   // covers s1 and s2 (contiguous)
  // 2. fused h-GEMM -> Bpack + s1/s2 (hbuf never materialized)
  gemm_h<<<dim3(4, 64, 2), 256, 0, stream>>>(xb, Wgp, a1, a2, Bpack, s1, s2);
  // 3. MFMA attention partials (128-row blocks, halved Bpack L2 traffic)
  attn_mfma8<<<dim3(64, 4), 512, 0, stream>>>(Bpack, s1, s2, adj, pacc, pl);
  // 4. finalize -> embed emitted directly as hi/lo split (llm inline)
  attn_finalize<<<8192, 256, 0, stream>>>(pacc, pl, bg, llm, ehi, elo);
  // 5. z1 = LR(embed @ W1 + b1) -> hi/lo
  gemm_mlp<<<dim3(8, 64), 256, 0, stream>>>(
      ehi, elo, W1ph, W1pl, b1, nullptr, z1hi, z1lo, 8192, 512, 768, MLP_SLOPE);
  // 6. z2 = LR(z1 @ W2 + b2) -> fp32
  gemm_mlp<<<dim3(4, 64), 256, 0, stream>>>(
      z1hi, z1lo, W2ph, W2pl, b2, z2, nullptr, nullptr, 8192, 256, 512, MLP_SLOPE);
  // 7. edge dots
  pred_kernel<<<(E * 64 + 255) / 256, 256, 0, stream>>>(z2, ts, out, E);
}